// Round 5
// baseline (131.220 us; speedup 1.0000x reference)
//
#include <hip/hip_runtime.h>
#include <hip/hip_bf16.h>
#include <math.h>

#define BT 48
#define N 1024
#define F 64
#define CIN 64
#define EM 16
#define LRELU_A 0.2f

typedef short bf16x8 __attribute__((ext_vector_type(8)));   // 8 bf16 = 4 VGPRs
typedef float f32x4  __attribute__((ext_vector_type(4)));

// exact RTNE float->bf16 bits (k_proj only, off hot path)
__device__ __forceinline__ unsigned short f2bf(float f) {
    unsigned int u = __float_as_uint(f);
    return (unsigned short)((u + 0x7FFFu + ((u >> 16) & 1u)) >> 16);
}

// ------------------------------------------------------------------
// k_proj_misc: blocks 0..767   : Wh row-block (64 rows) -> WhSw swizzled
//                                bf16 [bt][nb32][f][q][j] + s1/s2
//              blocks 768..895 : pack adj -> bitmask
//              blocks 896..899 : f1/f2 embedding scores
// (unchanged from round 4 — proven)
// ------------------------------------------------------------------
__global__ __launch_bounds__(256) void k_proj_misc(
    const float* __restrict__ x, const float* __restrict__ W,
    const float* __restrict__ a,
    const int* __restrict__ adj,
    const float* __restrict__ emb1, const float* __restrict__ emb2,
    const float* __restrict__ a2,
    unsigned short* __restrict__ WhSw,
    float* __restrict__ s1, float* __restrict__ s2,
    unsigned int* __restrict__ adjBits,
    float* __restrict__ f1, float* __restrict__ f2)
{
    const int tid = threadIdx.x;
    const int b   = blockIdx.x;

    if (b >= 768) {
        if (b < 896) {
            const int idx = (b - 768) * 256 + tid;
            const int r = idx >> 5, w32 = idx & 31;
            const int* p = adj + (size_t)r * N + w32 * 32;
            unsigned int m = 0;
#pragma unroll
            for (int j = 0; j < 32; ++j) m |= (p[j] > 0 ? 1u : 0u) << j;
            adjBits[idx] = m;
        } else {
            const int n = (b - 896) * 256 + tid;
            if (n < N) {
                float v1 = 0.f, v2 = 0.f;
#pragma unroll
                for (int k = 0; k < EM; ++k) {
                    v1 = fmaf(emb1[n * EM + k], a2[k], v1);
                    v2 = fmaf(emb2[n * EM + k], a2[EM + k], v2);
                }
                f1[n] = v1; f2[n] = v2;
            }
        }
        return;
    }

    __shared__ __align__(16) float sx[64 * 64];
    __shared__ __align__(16) float sWT[64 * 68];
    __shared__ __align__(16) unsigned short sT[64 * 80];

    const int bt  = b >> 4;
    const int n0  = (b & 15) * 64;
    const size_t grow = (size_t)bt * N + n0;

    {
        const float4* xv = (const float4*)(x + grow * CIN);
        float4* sxv = (float4*)sx;
        for (int i = tid; i < 64 * CIN / 4; i += 256) sxv[i] = xv[i];
        for (int i = tid; i < CIN * F; i += 256)
            sWT[(i & 63) * 68 + (i >> 6)] = W[i];
    }
    __syncthreads();

    const int f = tid & 63;
    const int w = tid >> 6;
    const float a1 = a[f], a2c = a[F + f];

    float acc[16];
#pragma unroll
    for (int t = 0; t < 16; ++t) acc[t] = 0.f;

    for (int cb = 0; cb < CIN; cb += 4) {
        const float4 wv = *(const float4*)&sWT[f * 68 + cb];
#pragma unroll
        for (int t = 0; t < 16; ++t) {
            const float4 xv = *(const float4*)&sx[(w * 16 + t) * 64 + cb];
            acc[t] = fmaf(xv.x, wv.x, acc[t]);
            acc[t] = fmaf(xv.y, wv.y, acc[t]);
            acc[t] = fmaf(xv.z, wv.z, acc[t]);
            acc[t] = fmaf(xv.w, wv.w, acc[t]);
        }
    }

#pragma unroll
    for (int t = 0; t < 16; ++t) {
        float v1 = acc[t] * a1;
        float v2 = acc[t] * a2c;
#pragma unroll
        for (int off = 32; off >= 1; off >>= 1) {
            v1 += __shfl_xor(v1, off, 64);
            v2 += __shfl_xor(v2, off, 64);
        }
        if (f == 0) {
            s1[grow + w * 16 + t] = v1;
            s2[grow + w * 16 + t] = v2;
        }
        sT[f * 80 + w * 16 + t] = f2bf(acc[t]);
    }
    __syncthreads();

    {
        const int ff = tid >> 2, q = tid & 3;
        const int nb0 = (b & 15) * 2;
#pragma unroll
        for (int nbL = 0; nbL < 2; ++nbL) {
            const size_t dst = ((size_t)(bt * 32 + nb0 + nbL) * 64 + ff) * 32 + q * 8;
            *(uint4*)&WhSw[dst] = *(const uint4*)&sT[ff * 80 + nbL * 32 + q * 8];
        }
    }
}

// ------------------------------------------------------------------
// k_attn round 5: double-buffered sB, ONE barrier per chunk.
// Body: issue loads(c+1) -> MFMA(c) from sB[c&1] -> exp/A-frag(c+1)
//       -> commit writes(c+1) to sB[(c+1)&1] -> barrier.
// writes(c+2) happen after barrier(c+1) which all waves reach only
// after MFMA(c) -> no buffer overwrite race. vmcnt drain at commit is
// covered by ~850 cyc of MFMA+exp. p~ = exp(max(A1+c, fma(c,.2,A2)))
// with A1=r-mhat, A2=.2r-mhat; mask via cndmask to -1e30 pre-exp.
// ------------------------------------------------------------------
__global__ __launch_bounds__(256, 3) void k_attn(
    const unsigned int* __restrict__ adjBits,
    const unsigned short* __restrict__ WhSw,
    const float* __restrict__ s1, const float* __restrict__ s2,
    const float* __restrict__ f1v, const float* __restrict__ f2v,
    float* __restrict__ out)
{
    __shared__ __align__(16) float sC[N];                   // 4 KB
    __shared__ __align__(16) unsigned short sB[2][8192];    // 2 x 16 KB

    const int tid  = threadIdx.x;
    const int xcd = blockIdx.x & 7;                         // XCD swizzle: 6 bt/XCD
    const int idx = blockIdx.x >> 3;
    const int bt  = xcd * 6 + (idx >> 4);
    const int i0  = (idx & 15) * 64;
    const int lane = tid & 63;
    const int w    = tid >> 6;
    const int q    = lane >> 4;
    const int m15  = lane & 15;

    for (int j = tid; j < N; j += 256) sC[j] = s2[bt * N + j] + f2v[j];
    __syncthreads();

    float mx = -1e30f;
#pragma unroll
    for (int t = 0; t < 4; ++t) {
        const float4 v = *(const float4*)&sC[t * 256 + lane * 4];
        mx = fmaxf(mx, fmaxf(fmaxf(v.x, v.y), fmaxf(v.z, v.w)));
    }
#pragma unroll
    for (int off = 32; off >= 1; off >>= 1) mx = fmaxf(mx, __shfl_xor(mx, off, 64));

    const int growq = i0 + w * 16 + m15;
    const float r    = s1[bt * N + growq] + f1v[growq];
    const float smx  = r + mx;
    const float mhat = fmaxf(smx, LRELU_A * smx);           // >= every e in row
    const float A1 = r - mhat;
    const float A2 = LRELU_A * r - mhat;
    float lsum = 0.f;

    const unsigned int* abRow = adjBits + growq * 32;
    const unsigned short* gBbt = WhSw + (size_t)bt * 65536;

    f32x4 acc[4];
#pragma unroll
    for (int ct = 0; ct < 4; ++ct)
#pragma unroll
        for (int e = 0; e < 4; ++e) acc[ct][e] = 0.f;

    auto stage_issue = [&](int ch, uint4* st) {
        const unsigned short* gB = gBbt + ch * 8192;
#pragma unroll
        for (int k = 0; k < 4; ++k)
            st[k] = *(const uint4*)(gB + k * 2048 + tid * 8);
    };
    auto make_afr = [&](int ch, bf16x8* afr) {
        const int k0 = ch * 128;
        const uint4 ab = *(const uint4*)&abRow[ch * 4];
        const unsigned int abw[4] = {ab.x, ab.y, ab.z, ab.w};
#pragma unroll
        for (int ks = 0; ks < 4; ++ks) {
            const float4 c0 = *(const float4*)&sC[k0 + ks * 32 + q * 8];
            const float4 c1 = *(const float4*)&sC[k0 + ks * 32 + q * 8 + 4];
            const float cj[8] = {c0.x, c0.y, c0.z, c0.w, c1.x, c1.y, c1.z, c1.w};
            const unsigned int mb = (abw[ks] >> (q * 8)) & 0xFFu;
            union { unsigned int u[4]; bf16x8 v; } A;
#pragma unroll
            for (int jp = 0; jp < 4; ++jp) {
                float t0 = fmaxf(A1 + cj[2 * jp],     fmaf(cj[2 * jp],     LRELU_A, A2));
                float t1 = fmaxf(A1 + cj[2 * jp + 1], fmaf(cj[2 * jp + 1], LRELU_A, A2));
                t0 = ((mb >> (2 * jp)) & 1u)     ? t0 : -1e30f;
                t1 = ((mb >> (2 * jp + 1)) & 1u) ? t1 : -1e30f;
                const float p0 = __expf(t0);        // masked -> exp(-1e30) = 0
                const float p1 = __expf(t1);
                lsum += p0 + p1;
                A.u[jp] = __builtin_amdgcn_perm(
                    __float_as_uint(p1) + 0x8000u,
                    __float_as_uint(p0) + 0x8000u, 0x07060302u);
            }
            afr[ks] = A.v;
        }
    };
    auto commit = [&](int ch, const uint4* st) {
        char* dst = (char*)sB[ch & 1];
#pragma unroll
        for (int k = 0; k < 4; ++k)
            *(uint4*)(dst + k * 4096 + tid * 16) = st[k];
    };
    auto mfma_chunk = [&](int ch, const bf16x8* afr) {
        const char* src = (const char*)sB[ch & 1];
#pragma unroll
        for (int ct = 0; ct < 4; ++ct)
#pragma unroll
            for (int ks = 0; ks < 4; ++ks) {
                const bf16x8 b = *(const bf16x8*)
                    (src + ks * 4096 + (ct * 16 + m15) * 64 + q * 16);
                acc[ct] = __builtin_amdgcn_mfma_f32_16x16x32_bf16(
                    afr[ks], b, acc[ct], 0, 0, 0);
            }
    };

    uint4 st[4];
    bf16x8 afrA[4], afrB[4];

    // prologue: chunk 0 staged + A-frags ready
    stage_issue(0, st);
    make_afr(0, afrA);
    commit(0, st);
    __syncthreads();

    for (int ch = 0; ch < 8; ++ch) {
        bf16x8* cur = (ch & 1) ? afrB : afrA;
        bf16x8* nxt = (ch & 1) ? afrA : afrB;
        if (ch < 7) stage_issue(ch + 1, st);
        mfma_chunk(ch, cur);
        if (ch < 7) {
            make_afr(ch + 1, nxt);
            commit(ch + 1, st);
        }
        __syncthreads();
    }

    // row denominators: lanes {l, l^16, l^32, l^48} share row m15
    lsum += __shfl_xor(lsum, 16, 64);
    lsum += __shfl_xor(lsum, 32, 64);

    float rinv[4];
#pragma unroll
    for (int reg = 0; reg < 4; ++reg)
        rinv[reg] = 1.f / __shfl(lsum, q * 4 + reg, 64);

#pragma unroll
    for (int ct = 0; ct < 4; ++ct) {
#pragma unroll
        for (int reg = 0; reg < 4; ++reg) {
            float h = acc[ct][reg] * rinv[reg];
            h = (h > 0.f) ? h : (__expf(h) - 1.f);          // ELU
            out[(size_t)(bt * N + i0 + w * 16 + q * 4 + reg) * F + ct * 16 + m15] = h;
        }
    }
}

// ------------------------------------------------------------------
extern "C" void kernel_launch(void* const* d_in, const int* in_sizes, int n_in,
                              void* d_out, int out_size, void* d_ws, size_t ws_size,
                              hipStream_t stream)
{
    const float* x    = (const float*)d_in[0];
    const int*   adj  = (const int*)  d_in[1];
    const float* emb1 = (const float*)d_in[2];
    const float* emb2 = (const float*)d_in[3];
    const float* W    = (const float*)d_in[4];
    const float* a    = (const float*)d_in[5];
    const float* a2   = (const float*)d_in[6];
    float* out = (float*)d_out;

    unsigned short* WhSw = (unsigned short*)d_ws;             // 6.29 MB
    float* s1 = (float*)(WhSw + (size_t)BT * 65536);
    float* s2 = s1 + BT * N;
    float* f1 = s2 + BT * N;
    float* f2 = f1 + N;
    unsigned int* adjBits = (unsigned int*)(f2 + N);          // 128 KB

    hipLaunchKernelGGL(k_proj_misc, dim3(900), dim3(256), 0, stream,
                       x, W, a, adj, emb1, emb2, a2, WhSw, s1, s2, adjBits, f1, f2);
    hipLaunchKernelGGL(k_attn, dim3(BT * 16), dim3(256), 0, stream,
                       adjBits, WhSw, s1, s2, f1, f2, out);
}

// Round 6
// 125.501 us; speedup vs baseline: 1.0456x; 1.0456x over previous
//
#include <hip/hip_runtime.h>
#include <hip/hip_bf16.h>
#include <math.h>

#define BT 48
#define N 1024
#define F 64
#define CIN 64
#define EM 16
#define LRELU_A 0.2f

typedef short bf16x8 __attribute__((ext_vector_type(8)));   // 8 bf16 = 4 VGPRs
typedef float f32x4  __attribute__((ext_vector_type(4)));

// exact RTNE float->bf16 bits (k_proj only, off hot path)
__device__ __forceinline__ unsigned short f2bf(float f) {
    unsigned int u = __float_as_uint(f);
    return (unsigned short)((u + 0x7FFFu + ((u >> 16) & 1u)) >> 16);
}

// ------------------------------------------------------------------
// k_proj_misc: blocks 0..767   : Wh row-block (64 rows) -> WhSw swizzled
//                                bf16 [bt][nb32][f][q][j] + s1/s2
//              blocks 768..895 : pack adj -> bitmask
//              blocks 896..899 : f1/f2 embedding scores
// (unchanged from round 4 — proven)
// ------------------------------------------------------------------
__global__ __launch_bounds__(256) void k_proj_misc(
    const float* __restrict__ x, const float* __restrict__ W,
    const float* __restrict__ a,
    const int* __restrict__ adj,
    const float* __restrict__ emb1, const float* __restrict__ emb2,
    const float* __restrict__ a2,
    unsigned short* __restrict__ WhSw,
    float* __restrict__ s1, float* __restrict__ s2,
    unsigned int* __restrict__ adjBits,
    float* __restrict__ f1, float* __restrict__ f2)
{
    const int tid = threadIdx.x;
    const int b   = blockIdx.x;

    if (b >= 768) {
        if (b < 896) {
            const int idx = (b - 768) * 256 + tid;
            const int r = idx >> 5, w32 = idx & 31;
            const int* p = adj + (size_t)r * N + w32 * 32;
            unsigned int m = 0;
#pragma unroll
            for (int j = 0; j < 32; ++j) m |= (p[j] > 0 ? 1u : 0u) << j;
            adjBits[idx] = m;
        } else {
            const int n = (b - 896) * 256 + tid;
            if (n < N) {
                float v1 = 0.f, v2 = 0.f;
#pragma unroll
                for (int k = 0; k < EM; ++k) {
                    v1 = fmaf(emb1[n * EM + k], a2[k], v1);
                    v2 = fmaf(emb2[n * EM + k], a2[EM + k], v2);
                }
                f1[n] = v1; f2[n] = v2;
            }
        }
        return;
    }

    __shared__ __align__(16) float sx[64 * 64];
    __shared__ __align__(16) float sWT[64 * 68];
    __shared__ __align__(16) unsigned short sT[64 * 80];

    const int bt  = b >> 4;
    const int n0  = (b & 15) * 64;
    const size_t grow = (size_t)bt * N + n0;

    {
        const float4* xv = (const float4*)(x + grow * CIN);
        float4* sxv = (float4*)sx;
        for (int i = tid; i < 64 * CIN / 4; i += 256) sxv[i] = xv[i];
        for (int i = tid; i < CIN * F; i += 256)
            sWT[(i & 63) * 68 + (i >> 6)] = W[i];
    }
    __syncthreads();

    const int f = tid & 63;
    const int w = tid >> 6;
    const float a1 = a[f], a2c = a[F + f];

    float acc[16];
#pragma unroll
    for (int t = 0; t < 16; ++t) acc[t] = 0.f;

    for (int cb = 0; cb < CIN; cb += 4) {
        const float4 wv = *(const float4*)&sWT[f * 68 + cb];
#pragma unroll
        for (int t = 0; t < 16; ++t) {
            const float4 xv = *(const float4*)&sx[(w * 16 + t) * 64 + cb];
            acc[t] = fmaf(xv.x, wv.x, acc[t]);
            acc[t] = fmaf(xv.y, wv.y, acc[t]);
            acc[t] = fmaf(xv.z, wv.z, acc[t]);
            acc[t] = fmaf(xv.w, wv.w, acc[t]);
        }
    }

#pragma unroll
    for (int t = 0; t < 16; ++t) {
        float v1 = acc[t] * a1;
        float v2 = acc[t] * a2c;
#pragma unroll
        for (int off = 32; off >= 1; off >>= 1) {
            v1 += __shfl_xor(v1, off, 64);
            v2 += __shfl_xor(v2, off, 64);
        }
        if (f == 0) {
            s1[grow + w * 16 + t] = v1;
            s2[grow + w * 16 + t] = v2;
        }
        sT[f * 80 + w * 16 + t] = f2bf(acc[t]);
    }
    __syncthreads();

    {
        const int ff = tid >> 2, q = tid & 3;
        const int nb0 = (b & 15) * 2;
#pragma unroll
        for (int nbL = 0; nbL < 2; ++nbL) {
            const size_t dst = ((size_t)(bt * 32 + nb0 + nbL) * 64 + ff) * 32 + q * 8;
            *(uint4*)&WhSw[dst] = *(const uint4*)&sT[ff * 80 + nbL * 32 + q * 8];
        }
    }
}

// ------------------------------------------------------------------
// k_attn round 6: double-buffered sB fed by global_load_lds DMA
// (width=16, zero VGPR round-trip, no ds_write phase), ONE barrier
// per chunk. Body: DMA(c+1)->sB[(c+1)&1]; MFMA(c) from sB[c&1];
// exp/A-frag(c+1); barrier (vmcnt drain covered by ~650cyc of work).
// All waves pass barrier(c-1) before iter c, so DMA(c+1) writing
// buf[(c-1)&1] cannot collide with MFMA(c-1) reads. A-layout, m^
// bound, epilogue proven in rounds 3-5.
// ------------------------------------------------------------------
__global__ __launch_bounds__(256, 3) void k_attn(
    const unsigned int* __restrict__ adjBits,
    const unsigned short* __restrict__ WhSw,
    const float* __restrict__ s1, const float* __restrict__ s2,
    const float* __restrict__ f1v, const float* __restrict__ f2v,
    float* __restrict__ out)
{
    __shared__ __align__(16) float sC[N];                   // 4 KB
    __shared__ __align__(16) unsigned short sB[2][8192];    // 2 x 16 KB

    const int tid  = threadIdx.x;
    const int xcd = blockIdx.x & 7;                         // XCD swizzle: 6 bt/XCD
    const int idx = blockIdx.x >> 3;
    const int bt  = xcd * 6 + (idx >> 4);
    const int i0  = (idx & 15) * 64;
    const int lane = tid & 63;
    const int w    = tid >> 6;
    const int q    = lane >> 4;
    const int m15  = lane & 15;

    for (int j = tid; j < N; j += 256) sC[j] = s2[bt * N + j] + f2v[j];
    __syncthreads();

    float mx = -1e30f;
#pragma unroll
    for (int t = 0; t < 4; ++t) {
        const float4 v = *(const float4*)&sC[t * 256 + lane * 4];
        mx = fmaxf(mx, fmaxf(fmaxf(v.x, v.y), fmaxf(v.z, v.w)));
    }
#pragma unroll
    for (int off = 32; off >= 1; off >>= 1) mx = fmaxf(mx, __shfl_xor(mx, off, 64));

    const int growq = i0 + w * 16 + m15;
    const float r    = s1[bt * N + growq] + f1v[growq];
    const float smx  = r + mx;
    const float mhat = fmaxf(smx, LRELU_A * smx);           // >= every e in row
    const float A1 = r - mhat;
    const float A2 = LRELU_A * r - mhat;
    float lsum = 0.f;

    const unsigned int* abRow = adjBits + growq * 32;
    const unsigned short* gBbt = WhSw + (size_t)bt * 65536;

    f32x4 acc[4];
#pragma unroll
    for (int ct = 0; ct < 4; ++ct)
#pragma unroll
        for (int e = 0; e < 4; ++e) acc[ct][e] = 0.f;

    // DMA chunk ch (16 KB) into sB[ch&1]: each wave copies its 4 KB
    // quarter as 4 issues of 1 KB (64 lanes x 16 B). LDS dest is
    // wave-uniform base (+ implicit lane*16); global src per-lane.
    auto dma = [&](int ch) {
        const unsigned short* src = gBbt + ch * 8192 + w * 2048 + lane * 8;
        unsigned short* dst = &sB[ch & 1][w * 2048];        // wave-uniform
#pragma unroll
        for (int it = 0; it < 4; ++it)
            __builtin_amdgcn_global_load_lds(
                (const __attribute__((address_space(1))) unsigned int*)(src + it * 512),
                (__attribute__((address_space(3))) unsigned int*)(dst + it * 512),
                16, 0, 0);
    };
    auto make_afr = [&](int ch, bf16x8* afr) {
        const int k0 = ch * 128;
        const uint4 ab = *(const uint4*)&abRow[ch * 4];
        const unsigned int abw[4] = {ab.x, ab.y, ab.z, ab.w};
#pragma unroll
        for (int ks = 0; ks < 4; ++ks) {
            const float4 c0 = *(const float4*)&sC[k0 + ks * 32 + q * 8];
            const float4 c1 = *(const float4*)&sC[k0 + ks * 32 + q * 8 + 4];
            const float cj[8] = {c0.x, c0.y, c0.z, c0.w, c1.x, c1.y, c1.z, c1.w};
            const unsigned int mb = (abw[ks] >> (q * 8)) & 0xFFu;
            union { unsigned int u[4]; bf16x8 v; } A;
#pragma unroll
            for (int jp = 0; jp < 4; ++jp) {
                float t0 = fmaxf(A1 + cj[2 * jp],     fmaf(cj[2 * jp],     LRELU_A, A2));
                float t1 = fmaxf(A1 + cj[2 * jp + 1], fmaf(cj[2 * jp + 1], LRELU_A, A2));
                t0 = ((mb >> (2 * jp)) & 1u)     ? t0 : -1e30f;
                t1 = ((mb >> (2 * jp + 1)) & 1u) ? t1 : -1e30f;
                const float p0 = __expf(t0);        // masked -> exp(-1e30) = 0
                const float p1 = __expf(t1);
                lsum += p0 + p1;
                A.u[jp] = __builtin_amdgcn_perm(
                    __float_as_uint(p1) + 0x8000u,
                    __float_as_uint(p0) + 0x8000u, 0x07060302u);
            }
            afr[ks] = A.v;
        }
    };
    auto mfma_chunk = [&](int ch, const bf16x8* afr) {
        const char* src = (const char*)sB[ch & 1];
#pragma unroll
        for (int ct = 0; ct < 4; ++ct)
#pragma unroll
            for (int ks = 0; ks < 4; ++ks) {
                const bf16x8 b = *(const bf16x8*)
                    (src + ks * 4096 + (ct * 16 + m15) * 64 + q * 16);
                acc[ct] = __builtin_amdgcn_mfma_f32_16x16x32_bf16(
                    afr[ks], b, acc[ct], 0, 0, 0);
            }
    };

    bf16x8 afrA[4], afrB[4];

    // prologue: DMA chunk 0, build its A-frags under the DMA latency
    dma(0);
    make_afr(0, afrA);
    __syncthreads();            // vmcnt(0) drain -> sB[0] ready

    for (int ch = 0; ch < 8; ++ch) {
        bf16x8* cur = (ch & 1) ? afrB : afrA;
        bf16x8* nxt = (ch & 1) ? afrA : afrB;
        if (ch < 7) {
            dma(ch + 1);
            mfma_chunk(ch, cur);
            make_afr(ch + 1, nxt);
            __syncthreads();    // drains DMA(ch+1); covered by MFMA+exp above
        } else {
            mfma_chunk(ch, cur);
        }
    }

    // row denominators: lanes {l, l^16, l^32, l^48} share row m15
    lsum += __shfl_xor(lsum, 16, 64);
    lsum += __shfl_xor(lsum, 32, 64);

    float rinv[4];
#pragma unroll
    for (int reg = 0; reg < 4; ++reg)
        rinv[reg] = 1.f / __shfl(lsum, q * 4 + reg, 64);

#pragma unroll
    for (int ct = 0; ct < 4; ++ct) {
#pragma unroll
        for (int reg = 0; reg < 4; ++reg) {
            float h = acc[ct][reg] * rinv[reg];
            h = (h > 0.f) ? h : (__expf(h) - 1.f);          // ELU
            out[(size_t)(bt * N + i0 + w * 16 + q * 4 + reg) * F + ct * 16 + m15] = h;
        }
    }
}

// ------------------------------------------------------------------
extern "C" void kernel_launch(void* const* d_in, const int* in_sizes, int n_in,
                              void* d_out, int out_size, void* d_ws, size_t ws_size,
                              hipStream_t stream)
{
    const float* x    = (const float*)d_in[0];
    const int*   adj  = (const int*)  d_in[1];
    const float* emb1 = (const float*)d_in[2];
    const float* emb2 = (const float*)d_in[3];
    const float* W    = (const float*)d_in[4];
    const float* a    = (const float*)d_in[5];
    const float* a2   = (const float*)d_in[6];
    float* out = (float*)d_out;

    unsigned short* WhSw = (unsigned short*)d_ws;             // 6.29 MB
    float* s1 = (float*)(WhSw + (size_t)BT * 65536);
    float* s2 = s1 + BT * N;
    float* f1 = s2 + BT * N;
    float* f2 = f1 + N;
    unsigned int* adjBits = (unsigned int*)(f2 + N);          // 128 KB

    hipLaunchKernelGGL(k_proj_misc, dim3(900), dim3(256), 0, stream,
                       x, W, a, adj, emb1, emb2, a2, WhSw, s1, s2, adjBits, f1, f2);
    hipLaunchKernelGGL(k_attn, dim3(BT * 16), dim3(256), 0, stream,
                       adjBits, WhSw, s1, s2, f1, f2, out);
}

// Round 7
// 125.339 us; speedup vs baseline: 1.0469x; 1.0013x over previous
//
#include <hip/hip_runtime.h>
#include <hip/hip_bf16.h>
#include <math.h>

#define BT 48
#define N 1024
#define F 64
#define CIN 64
#define EM 16
#define LRELU_A 0.2f
#define L2E 1.4426950408889634f

#if __has_builtin(__builtin_amdgcn_exp2f)
#define EXP2(x) __builtin_amdgcn_exp2f(x)
#else
#define EXP2(x) exp2f(x)
#endif

typedef short bf16x8 __attribute__((ext_vector_type(8)));   // 8 bf16 = 4 VGPRs
typedef float f32x4  __attribute__((ext_vector_type(4)));

// exact RTNE float->bf16 bits (k_proj only, off hot path)
__device__ __forceinline__ unsigned short f2bf(float f) {
    unsigned int u = __float_as_uint(f);
    return (unsigned short)((u + 0x7FFFu + ((u >> 16) & 1u)) >> 16);
}

// ------------------------------------------------------------------
// k_proj_misc: blocks 0..767   : Wh row-block (64 rows) -> WhSw swizzled
//   bf16 [bt][nb32][f][slot][j] where k-sub-quad q of row f is stored at
//   slot (q+f)&3  (XOR swizzle -> conflict-free B-frag ds_reads in k_attn)
//              blocks 768..895 : pack adj -> bitmask
//              blocks 896..899 : f1/f2 embedding scores
// ------------------------------------------------------------------
__global__ __launch_bounds__(256) void k_proj_misc(
    const float* __restrict__ x, const float* __restrict__ W,
    const float* __restrict__ a,
    const int* __restrict__ adj,
    const float* __restrict__ emb1, const float* __restrict__ emb2,
    const float* __restrict__ a2,
    unsigned short* __restrict__ WhSw,
    float* __restrict__ s1, float* __restrict__ s2,
    unsigned int* __restrict__ adjBits,
    float* __restrict__ f1, float* __restrict__ f2)
{
    const int tid = threadIdx.x;
    const int b   = blockIdx.x;

    if (b >= 768) {
        if (b < 896) {
            const int idx = (b - 768) * 256 + tid;
            const int r = idx >> 5, w32 = idx & 31;
            const int* p = adj + (size_t)r * N + w32 * 32;
            unsigned int m = 0;
#pragma unroll
            for (int j = 0; j < 32; ++j) m |= (p[j] > 0 ? 1u : 0u) << j;
            adjBits[idx] = m;
        } else {
            const int n = (b - 896) * 256 + tid;
            if (n < N) {
                float v1 = 0.f, v2 = 0.f;
#pragma unroll
                for (int k = 0; k < EM; ++k) {
                    v1 = fmaf(emb1[n * EM + k], a2[k], v1);
                    v2 = fmaf(emb2[n * EM + k], a2[EM + k], v2);
                }
                f1[n] = v1; f2[n] = v2;
            }
        }
        return;
    }

    __shared__ __align__(16) float sx[64 * 64];
    __shared__ __align__(16) float sWT[64 * 68];
    __shared__ __align__(16) unsigned short sT[64 * 80];

    const int bt  = b >> 4;
    const int n0  = (b & 15) * 64;
    const size_t grow = (size_t)bt * N + n0;

    {
        const float4* xv = (const float4*)(x + grow * CIN);
        float4* sxv = (float4*)sx;
        for (int i = tid; i < 64 * CIN / 4; i += 256) sxv[i] = xv[i];
        for (int i = tid; i < CIN * F; i += 256)
            sWT[(i & 63) * 68 + (i >> 6)] = W[i];
    }
    __syncthreads();

    const int f = tid & 63;
    const int w = tid >> 6;
    const float a1 = a[f], a2c = a[F + f];

    float acc[16];
#pragma unroll
    for (int t = 0; t < 16; ++t) acc[t] = 0.f;

    for (int cb = 0; cb < CIN; cb += 4) {
        const float4 wv = *(const float4*)&sWT[f * 68 + cb];
#pragma unroll
        for (int t = 0; t < 16; ++t) {
            const float4 xv = *(const float4*)&sx[(w * 16 + t) * 64 + cb];
            acc[t] = fmaf(xv.x, wv.x, acc[t]);
            acc[t] = fmaf(xv.y, wv.y, acc[t]);
            acc[t] = fmaf(xv.z, wv.z, acc[t]);
            acc[t] = fmaf(xv.w, wv.w, acc[t]);
        }
    }

#pragma unroll
    for (int t = 0; t < 16; ++t) {
        float v1 = acc[t] * a1;
        float v2 = acc[t] * a2c;
#pragma unroll
        for (int off = 32; off >= 1; off >>= 1) {
            v1 += __shfl_xor(v1, off, 64);
            v2 += __shfl_xor(v2, off, 64);
        }
        if (f == 0) {
            s1[grow + w * 16 + t] = v1;
            s2[grow + w * 16 + t] = v2;
        }
        sT[f * 80 + w * 16 + t] = f2bf(acc[t]);
    }
    __syncthreads();

    // store with q-slot XOR swizzle: k-sub q -> slot (q+ff)&3
    {
        const int ff = tid >> 2, q = tid & 3;
        const int slot = (q + ff) & 3;
        const int nb0 = (b & 15) * 2;
#pragma unroll
        for (int nbL = 0; nbL < 2; ++nbL) {
            const size_t dst = ((size_t)(bt * 32 + nb0 + nbL) * 64 + ff) * 32 + slot * 8;
            *(uint4*)&WhSw[dst] = *(const uint4*)&sT[ff * 80 + nbL * 32 + q * 8];
        }
    }
}

// ------------------------------------------------------------------
// k_attn round 7: round-6 DMA double-buffer + (a) XOR-swizzled B-frag
// reads (conflict-free ds_read_b128: bank-start spread across sweeps),
// (b) exp2-domain softmax (log2e folded into sC/A1/A2 -> v_exp direct).
// ------------------------------------------------------------------
__global__ __launch_bounds__(256, 3) void k_attn(
    const unsigned int* __restrict__ adjBits,
    const unsigned short* __restrict__ WhSw,
    const float* __restrict__ s1, const float* __restrict__ s2,
    const float* __restrict__ f1v, const float* __restrict__ f2v,
    float* __restrict__ out)
{
    __shared__ __align__(16) float sC[N];                   // 4 KB (pre-scaled by log2e)
    __shared__ __align__(16) unsigned short sB[2][8192];    // 2 x 16 KB

    const int tid  = threadIdx.x;
    const int xcd = blockIdx.x & 7;                         // XCD swizzle: 6 bt/XCD
    const int idx = blockIdx.x >> 3;
    const int bt  = xcd * 6 + (idx >> 4);
    const int i0  = (idx & 15) * 64;
    const int lane = tid & 63;
    const int w    = tid >> 6;
    const int q    = lane >> 4;
    const int m15  = lane & 15;

    for (int j = tid; j < N; j += 256) sC[j] = (s2[bt * N + j] + f2v[j]) * L2E;
    __syncthreads();

    float mx = -1e30f;
#pragma unroll
    for (int t = 0; t < 4; ++t) {
        const float4 v = *(const float4*)&sC[t * 256 + lane * 4];
        mx = fmaxf(mx, fmaxf(fmaxf(v.x, v.y), fmaxf(v.z, v.w)));
    }
#pragma unroll
    for (int off = 32; off >= 1; off >>= 1) mx = fmaxf(mx, __shfl_xor(mx, off, 64));

    const int growq = i0 + w * 16 + m15;
    const float r    = (s1[bt * N + growq] + f1v[growq]) * L2E;   // scaled domain
    const float smx  = r + mx;
    const float mhat = fmaxf(smx, LRELU_A * smx);           // >= every scaled e in row
    const float A1 = r - mhat;
    const float A2 = LRELU_A * r - mhat;
    float lsum = 0.f;

    const unsigned int* abRow = adjBits + growq * 32;
    const unsigned short* gBbt = WhSw + (size_t)bt * 65536;

    f32x4 acc[4];
#pragma unroll
    for (int ct = 0; ct < 4; ++ct)
#pragma unroll
        for (int e = 0; e < 4; ++e) acc[ct][e] = 0.f;

    // DMA chunk ch (16 KB) into sB[ch&1]; byte-copy preserves the swizzle.
    auto dma = [&](int ch) {
        const unsigned short* src = gBbt + ch * 8192 + w * 2048 + lane * 8;
        unsigned short* dst = &sB[ch & 1][w * 2048];        // wave-uniform base
#pragma unroll
        for (int it = 0; it < 4; ++it)
            __builtin_amdgcn_global_load_lds(
                (const __attribute__((address_space(1))) unsigned int*)(src + it * 512),
                (__attribute__((address_space(3))) unsigned int*)(dst + it * 512),
                16, 0, 0);
    };
    auto make_afr = [&](int ch, bf16x8* afr) {
        const int k0 = ch * 128;
        const uint4 ab = *(const uint4*)&abRow[ch * 4];
        const unsigned int abw[4] = {ab.x, ab.y, ab.z, ab.w};
#pragma unroll
        for (int ks = 0; ks < 4; ++ks) {
            const float4 c0 = *(const float4*)&sC[k0 + ks * 32 + q * 8];
            const float4 c1 = *(const float4*)&sC[k0 + ks * 32 + q * 8 + 4];
            const float cj[8] = {c0.x, c0.y, c0.z, c0.w, c1.x, c1.y, c1.z, c1.w};
            const unsigned int mb = (abw[ks] >> (q * 8)) & 0xFFu;
            union { unsigned int u[4]; bf16x8 v; } A;
#pragma unroll
            for (int jp = 0; jp < 4; ++jp) {
                float t0 = fmaxf(A1 + cj[2 * jp],     fmaf(cj[2 * jp],     LRELU_A, A2));
                float t1 = fmaxf(A1 + cj[2 * jp + 1], fmaf(cj[2 * jp + 1], LRELU_A, A2));
                t0 = ((mb >> (2 * jp)) & 1u)     ? t0 : -1e30f;
                t1 = ((mb >> (2 * jp + 1)) & 1u) ? t1 : -1e30f;
                const float p0 = EXP2(t0);          // masked -> 0
                const float p1 = EXP2(t1);
                lsum += p0 + p1;
                A.u[jp] = __builtin_amdgcn_perm(
                    __float_as_uint(p1) + 0x8000u,
                    __float_as_uint(p0) + 0x8000u, 0x07060302u);
            }
            afr[ks] = A.v;
        }
    };
    auto mfma_chunk = [&](int ch, const bf16x8* afr) {
        const char* src = (const char*)sB[ch & 1];
        // swizzled read: row = ct*16+m15, slot = (q+m15)&3 holds k-sub q
        const int slotoff = ((q + m15) & 3) * 16;
#pragma unroll
        for (int ct = 0; ct < 4; ++ct)
#pragma unroll
            for (int ks = 0; ks < 4; ++ks) {
                const bf16x8 b = *(const bf16x8*)
                    (src + ks * 4096 + (ct * 16 + m15) * 64 + slotoff);
                acc[ct] = __builtin_amdgcn_mfma_f32_16x16x32_bf16(
                    afr[ks], b, acc[ct], 0, 0, 0);
            }
    };

    bf16x8 afrA[4], afrB[4];

    dma(0);
    make_afr(0, afrA);
    __syncthreads();            // vmcnt(0) drain -> sB[0] ready

    for (int ch = 0; ch < 8; ++ch) {
        bf16x8* cur = (ch & 1) ? afrB : afrA;
        bf16x8* nxt = (ch & 1) ? afrA : afrB;
        if (ch < 7) {
            dma(ch + 1);
            mfma_chunk(ch, cur);
            make_afr(ch + 1, nxt);
            __syncthreads();    // drains DMA(ch+1); covered by MFMA+exp above
        } else {
            mfma_chunk(ch, cur);
        }
    }

    // row denominators: lanes {l, l^16, l^32, l^48} share row m15
    lsum += __shfl_xor(lsum, 16, 64);
    lsum += __shfl_xor(lsum, 32, 64);

    float rinv[4];
#pragma unroll
    for (int reg = 0; reg < 4; ++reg)
        rinv[reg] = 1.f / __shfl(lsum, q * 4 + reg, 64);

#pragma unroll
    for (int ct = 0; ct < 4; ++ct) {
#pragma unroll
        for (int reg = 0; reg < 4; ++reg) {
            float h = acc[ct][reg] * rinv[reg];
            h = (h > 0.f) ? h : (__expf(h) - 1.f);          // ELU
            out[(size_t)(bt * N + i0 + w * 16 + q * 4 + reg) * F + ct * 16 + m15] = h;
        }
    }
}

// ------------------------------------------------------------------
extern "C" void kernel_launch(void* const* d_in, const int* in_sizes, int n_in,
                              void* d_out, int out_size, void* d_ws, size_t ws_size,
                              hipStream_t stream)
{
    const float* x    = (const float*)d_in[0];
    const int*   adj  = (const int*)  d_in[1];
    const float* emb1 = (const float*)d_in[2];
    const float* emb2 = (const float*)d_in[3];
    const float* W    = (const float*)d_in[4];
    const float* a    = (const float*)d_in[5];
    const float* a2   = (const float*)d_in[6];
    float* out = (float*)d_out;

    unsigned short* WhSw = (unsigned short*)d_ws;             // 6.29 MB
    float* s1 = (float*)(WhSw + (size_t)BT * 65536);
    float* s2 = s1 + BT * N;
    float* f1 = s2 + BT * N;
    float* f2 = f1 + N;
    unsigned int* adjBits = (unsigned int*)(f2 + N);          // 128 KB

    hipLaunchKernelGGL(k_proj_misc, dim3(900), dim3(256), 0, stream,
                       x, W, a, adj, emb1, emb2, a2, WhSw, s1, s2, adjBits, f1, f2);
    hipLaunchKernelGGL(k_attn, dim3(BT * 16), dim3(256), 0, stream,
                       adjBits, WhSw, s1, s2, f1, f2, out);
}

// Round 9
// 120.328 us; speedup vs baseline: 1.0905x; 1.0416x over previous
//
#include <hip/hip_runtime.h>
#include <hip/hip_bf16.h>
#include <math.h>

#define BT 48
#define N 1024
#define F 64
#define CIN 64
#define EM 16
#define LRELU_A 0.2f
#define L2E 1.4426950408889634f

typedef short bf16x8 __attribute__((ext_vector_type(8)));   // 8 bf16 = 4 VGPRs
typedef float f32x4  __attribute__((ext_vector_type(4)));

// exact RTNE float->bf16 bits (k_proj only, off hot path)
__device__ __forceinline__ unsigned short f2bf(float f) {
    unsigned int u = __float_as_uint(f);
    return (unsigned short)((u + 0x7FFFu + ((u >> 16) & 1u)) >> 16);
}

// ------------------------------------------------------------------
// k_proj_misc (unchanged from round 7 — proven):
//  blocks 0..767: Wh row-block -> WhSw bf16 [bt][nb32][f][slot][j],
//    slot=(q+f)&3 XOR swizzle; + s1/s2 wave reductions.
//  blocks 768..895: adj bit-pack. blocks 896..899: f1/f2.
// ------------------------------------------------------------------
__global__ __launch_bounds__(256) void k_proj_misc(
    const float* __restrict__ x, const float* __restrict__ W,
    const float* __restrict__ a,
    const int* __restrict__ adj,
    const float* __restrict__ emb1, const float* __restrict__ emb2,
    const float* __restrict__ a2,
    unsigned short* __restrict__ WhSw,
    float* __restrict__ s1, float* __restrict__ s2,
    unsigned int* __restrict__ adjBits,
    float* __restrict__ f1, float* __restrict__ f2)
{
    const int tid = threadIdx.x;
    const int b   = blockIdx.x;

    if (b >= 768) {
        if (b < 896) {
            const int idx = (b - 768) * 256 + tid;
            const int r = idx >> 5, w32 = idx & 31;
            const int* p = adj + (size_t)r * N + w32 * 32;
            unsigned int m = 0;
#pragma unroll
            for (int j = 0; j < 32; ++j) m |= (p[j] > 0 ? 1u : 0u) << j;
            adjBits[idx] = m;
        } else {
            const int n = (b - 896) * 256 + tid;
            if (n < N) {
                float v1 = 0.f, v2 = 0.f;
#pragma unroll
                for (int k = 0; k < EM; ++k) {
                    v1 = fmaf(emb1[n * EM + k], a2[k], v1);
                    v2 = fmaf(emb2[n * EM + k], a2[EM + k], v2);
                }
                f1[n] = v1; f2[n] = v2;
            }
        }
        return;
    }

    __shared__ __align__(16) float sx[64 * 64];
    __shared__ __align__(16) float sWT[64 * 68];
    __shared__ __align__(16) unsigned short sT[64 * 80];

    const int bt  = b >> 4;
    const int n0  = (b & 15) * 64;
    const size_t grow = (size_t)bt * N + n0;

    {
        const float4* xv = (const float4*)(x + grow * CIN);
        float4* sxv = (float4*)sx;
        for (int i = tid; i < 64 * CIN / 4; i += 256) sxv[i] = xv[i];
        for (int i = tid; i < CIN * F; i += 256)
            sWT[(i & 63) * 68 + (i >> 6)] = W[i];
    }
    __syncthreads();

    const int f = tid & 63;
    const int w = tid >> 6;
    const float a1 = a[f], a2c = a[F + f];

    float acc[16];
#pragma unroll
    for (int t = 0; t < 16; ++t) acc[t] = 0.f;

    for (int cb = 0; cb < CIN; cb += 4) {
        const float4 wv = *(const float4*)&sWT[f * 68 + cb];
#pragma unroll
        for (int t = 0; t < 16; ++t) {
            const float4 xv = *(const float4*)&sx[(w * 16 + t) * 64 + cb];
            acc[t] = fmaf(xv.x, wv.x, acc[t]);
            acc[t] = fmaf(xv.y, wv.y, acc[t]);
            acc[t] = fmaf(xv.z, wv.z, acc[t]);
            acc[t] = fmaf(xv.w, wv.w, acc[t]);
        }
    }

#pragma unroll
    for (int t = 0; t < 16; ++t) {
        float v1 = acc[t] * a1;
        float v2 = acc[t] * a2c;
#pragma unroll
        for (int off = 32; off >= 1; off >>= 1) {
            v1 += __shfl_xor(v1, off, 64);
            v2 += __shfl_xor(v2, off, 64);
        }
        if (f == 0) {
            s1[grow + w * 16 + t] = v1;
            s2[grow + w * 16 + t] = v2;
        }
        sT[f * 80 + w * 16 + t] = f2bf(acc[t]);
    }
    __syncthreads();

    {
        const int ff = tid >> 2, q = tid & 3;
        const int slot = (q + ff) & 3;
        const int nb0 = (b & 15) * 2;
#pragma unroll
        for (int nbL = 0; nbL < 2; ++nbL) {
            const size_t dst = ((size_t)(bt * 32 + nb0 + nbL) * 64 + ff) * 32 + slot * 8;
            *(uint4*)&WhSw[dst] = *(const uint4*)&sT[ff * 80 + nbL * 32 + q * 8];
        }
    }
}

// ------------------------------------------------------------------
// k_attn round 9: round-7 structure (DMA double-buffer, XOR-swizzled B,
// single barrier/chunk) + FACTORIZED softmax: rank-1 scores mean
//   pos branch: exp2(r+c-m^) = E1*X1,  E1=2^(r-m^),  X1=2^c
//   neg branch: exp2(.2(r+c)-m^) = E2*X2, E2=2^(.2r-m^), X2=2^(.2c)
//   branch sel: c > -r  <=>  X1 > T, T=2^(-r)  (tie -> both equal)
// X1/X2 staged per block (2048 exps); E1/E2/T per lane (3 exps).
// Inner loop: NO transcendentals, ~8 full-rate VALU/p.
// ------------------------------------------------------------------
__global__ __launch_bounds__(256, 3) void k_attn(
    const unsigned int* __restrict__ adjBits,
    const unsigned short* __restrict__ WhSw,
    const float* __restrict__ s1, const float* __restrict__ s2,
    const float* __restrict__ f1v, const float* __restrict__ f2v,
    float* __restrict__ out)
{
    __shared__ __align__(16) float sX1[N];                  // 2^c   (scaled domain)
    __shared__ __align__(16) float sX2[N];                  // 2^.2c
    __shared__ __align__(16) unsigned short sB[2][8192];    // 2 x 16 KB
    __shared__ float sWmax[4];

    const int tid  = threadIdx.x;
    const int xcd = blockIdx.x & 7;                         // XCD swizzle: 6 bt/XCD
    const int idx = blockIdx.x >> 3;
    const int bt  = xcd * 6 + (idx >> 4);
    const int i0  = (idx & 15) * 64;
    const int lane = tid & 63;
    const int w    = tid >> 6;
    const int q    = lane >> 4;
    const int m15  = lane & 15;

    // stage X1/X2 and track block max of c (scaled by log2e)
    float cmax = -1e30f;
    for (int j = tid; j < N; j += 256) {
        const float c = (s2[bt * N + j] + f2v[j]) * L2E;
        sX1[j] = exp2f(c);
        sX2[j] = exp2f(LRELU_A * c);
        cmax = fmaxf(cmax, c);
    }
#pragma unroll
    for (int off = 32; off >= 1; off >>= 1) cmax = fmaxf(cmax, __shfl_xor(cmax, off, 64));
    if (lane == 0) sWmax[w] = cmax;
    __syncthreads();
    const float mx = fmaxf(fmaxf(sWmax[0], sWmax[1]), fmaxf(sWmax[2], sWmax[3]));

    const int growq = i0 + w * 16 + m15;
    const float r    = (s1[bt * N + growq] + f1v[growq]) * L2E;   // scaled domain
    const float smx  = r + mx;
    const float mhat = fmaxf(smx, LRELU_A * smx);           // >= every scaled e in row
    const float E1 = exp2f(r - mhat);
    const float E2 = exp2f(LRELU_A * r - mhat);
    const float T  = exp2f(-r);                             // X1 > T <=> c > -r
    float lsum = 0.f;

    const unsigned int* abRow = adjBits + growq * 32;
    const unsigned short* gBbt = WhSw + (size_t)bt * 65536;

    f32x4 acc[4];
#pragma unroll
    for (int ct = 0; ct < 4; ++ct)
#pragma unroll
        for (int e = 0; e < 4; ++e) acc[ct][e] = 0.f;

    auto dma = [&](int ch) {
        const unsigned short* src = gBbt + ch * 8192 + w * 2048 + lane * 8;
        unsigned short* dst = &sB[ch & 1][w * 2048];        // wave-uniform base
#pragma unroll
        for (int it = 0; it < 4; ++it)
            __builtin_amdgcn_global_load_lds(
                (const __attribute__((address_space(1))) unsigned int*)(src + it * 512),
                (__attribute__((address_space(3))) unsigned int*)(dst + it * 512),
                16, 0, 0);
    };
    auto make_afr = [&](int ch, bf16x8* afr) {
        const int k0 = ch * 128;
        const uint4 ab = *(const uint4*)&abRow[ch * 4];
        const unsigned int abw[4] = {ab.x, ab.y, ab.z, ab.w};
#pragma unroll
        for (int ks = 0; ks < 4; ++ks) {
            const int jb = k0 + ks * 32 + q * 8;
            const float4 x1a = *(const float4*)&sX1[jb];
            const float4 x1b = *(const float4*)&sX1[jb + 4];
            const float4 x2a = *(const float4*)&sX2[jb];
            const float4 x2b = *(const float4*)&sX2[jb + 4];
            const float X1[8] = {x1a.x, x1a.y, x1a.z, x1a.w, x1b.x, x1b.y, x1b.z, x1b.w};
            const float X2[8] = {x2a.x, x2a.y, x2a.z, x2a.w, x2b.x, x2b.y, x2b.z, x2b.w};
            const unsigned int mb = (abw[ks] >> (q * 8)) & 0xFFu;
            union { unsigned int u[4]; bf16x8 v; } A;
#pragma unroll
            for (int jp = 0; jp < 4; ++jp) {
                const bool s0 = X1[2 * jp]     > T;
                const bool s1b = X1[2 * jp + 1] > T;
                float p0 = (s0  ? X1[2 * jp]     : X2[2 * jp])     * (s0  ? E1 : E2);
                float p1 = (s1b ? X1[2 * jp + 1] : X2[2 * jp + 1]) * (s1b ? E1 : E2);
                p0 = ((mb >> (2 * jp)) & 1u)     ? p0 : 0.f;
                p1 = ((mb >> (2 * jp + 1)) & 1u) ? p1 : 0.f;
                lsum += p0 + p1;
                A.u[jp] = __builtin_amdgcn_perm(
                    __float_as_uint(p1) + 0x8000u,
                    __float_as_uint(p0) + 0x8000u, 0x07060302u);
            }
            afr[ks] = A.v;
        }
    };
    auto mfma_chunk = [&](int ch, const bf16x8* afr) {
        const char* src = (const char*)sB[ch & 1];
        const int slotoff = ((q + m15) & 3) * 16;           // XOR-swizzled slot
#pragma unroll
        for (int ct = 0; ct < 4; ++ct)
#pragma unroll
            for (int ks = 0; ks < 4; ++ks) {
                const bf16x8 bb = *(const bf16x8*)
                    (src + ks * 4096 + (ct * 16 + m15) * 64 + slotoff);
                acc[ct] = __builtin_amdgcn_mfma_f32_16x16x32_bf16(
                    afr[ks], bb, acc[ct], 0, 0, 0);
            }
    };

    bf16x8 afrA[4], afrB[4];

    dma(0);
    make_afr(0, afrA);
    __syncthreads();            // vmcnt drain -> sB[0] ready

    for (int ch = 0; ch < 8; ++ch) {
        bf16x8* cur = (ch & 1) ? afrB : afrA;
        bf16x8* nxt = (ch & 1) ? afrA : afrB;
        if (ch < 7) {
            dma(ch + 1);
            mfma_chunk(ch, cur);
            make_afr(ch + 1, nxt);
            __syncthreads();    // drains DMA(ch+1); covered by MFMA + select work
        } else {
            mfma_chunk(ch, cur);
        }
    }

    // row denominators: lanes {l, l^16, l^32, l^48} share row m15
    lsum += __shfl_xor(lsum, 16, 64);
    lsum += __shfl_xor(lsum, 32, 64);

    float rinv[4];
#pragma unroll
    for (int reg = 0; reg < 4; ++reg)
        rinv[reg] = 1.f / __shfl(lsum, q * 4 + reg, 64);

#pragma unroll
    for (int ct = 0; ct < 4; ++ct) {
#pragma unroll
        for (int reg = 0; reg < 4; ++reg) {
            float h = acc[ct][reg] * rinv[reg];
            h = (h > 0.f) ? h : (__expf(h) - 1.f);          // ELU
            out[(size_t)(bt * N + i0 + w * 16 + q * 4 + reg) * F + ct * 16 + m15] = h;
        }
    }
}

// ------------------------------------------------------------------
extern "C" void kernel_launch(void* const* d_in, const int* in_sizes, int n_in,
                              void* d_out, int out_size, void* d_ws, size_t ws_size,
                              hipStream_t stream)
{
    const float* x    = (const float*)d_in[0];
    const int*   adj  = (const int*)  d_in[1];
    const float* emb1 = (const float*)d_in[2];
    const float* emb2 = (const float*)d_in[3];
    const float* W    = (const float*)d_in[4];
    const float* a    = (const float*)d_in[5];
    const float* a2   = (const float*)d_in[6];
    float* out = (float*)d_out;

    unsigned short* WhSw = (unsigned short*)d_ws;             // 6.29 MB
    float* s1 = (float*)(WhSw + (size_t)BT * 65536);
    float* s2 = s1 + BT * N;
    float* f1 = s2 + BT * N;
    float* f2 = f1 + N;
    unsigned int* adjBits = (unsigned int*)(f2 + N);          // 128 KB

    hipLaunchKernelGGL(k_proj_misc, dim3(900), dim3(256), 0, stream,
                       x, W, a, adj, emb1, emb2, a2, WhSw, s1, s2, adjBits, f1, f2);
    hipLaunchKernelGGL(k_attn, dim3(BT * 16), dim3(256), 0, stream,
                       adjBits, WhSw, s1, s2, f1, f2, out);
}